// Round 1
// baseline (1029.587 us; speedup 1.0000x reference)
//
#include <hip/hip_runtime.h>
#include <math.h>

namespace {
constexpr int B_  = 2;
constexpr int T_  = 2048;
constexpr int D_  = 1024;
constexpr int H_  = 16;
constexpr int DH_ = 64;
constexpr int M_  = B_ * T_;   // 4096 rows of x
}

// ---------------------------------------------------------------------------
// GEMM: C = A @ W^T.   A:[M,K] row-major, W:[N,K] row-major (torch Linear).
// Tile 128(M) x 64(N), BK=16, 256 threads, 8x4 micro-tile.
// remap_bhtd != 0: store C at [b,h,t,dh] (for Q/K/V) instead of [m,n].
// ---------------------------------------------------------------------------
__global__ __launch_bounds__(256)
void gemm_abt(const float* __restrict__ A, const float* __restrict__ W,
              float* __restrict__ C, const int M, const int N, const int K,
              const int remap_bhtd)
{
    constexpr int BM = 128, BN = 64, BK = 16;
    __shared__ float As[BK][BM + 4];   // [k][m], stride 132 (16B aligned)
    __shared__ float Bs[BK][BN + 4];   // [k][n], stride 68

    const int tid = threadIdx.x;
    const int tx  = tid & 15;          // n dim (16)
    const int ty  = tid >> 4;          // m dim (16)
    const int m0  = blockIdx.y * BM;
    const int n0  = blockIdx.x * BN;

    float acc[8][4];
#pragma unroll
    for (int i = 0; i < 8; ++i)
#pragma unroll
        for (int j = 0; j < 4; ++j) acc[i][j] = 0.f;

    const int lr = tid >> 2;           // 0..63
    const int lk = (tid & 3) << 2;     // 0,4,8,12

    for (int k0 = 0; k0 < K; k0 += BK) {
        {   // W tile: 64 rows x 16 k, one float4 per thread (transposing write)
            const float4 b4 = *reinterpret_cast<const float4*>(
                &W[(size_t)(n0 + lr) * K + (k0 + lk)]);
            Bs[lk + 0][lr] = b4.x; Bs[lk + 1][lr] = b4.y;
            Bs[lk + 2][lr] = b4.z; Bs[lk + 3][lr] = b4.w;
        }
#pragma unroll
        for (int it = 0; it < 2; ++it) {  // A tile: 128 x 16, two float4/thread
            const int r = lr + (it << 6);
            const float4 a4 = *reinterpret_cast<const float4*>(
                &A[(size_t)(m0 + r) * K + (k0 + lk)]);
            As[lk + 0][r] = a4.x; As[lk + 1][r] = a4.y;
            As[lk + 2][r] = a4.z; As[lk + 3][r] = a4.w;
        }
        __syncthreads();
#pragma unroll
        for (int kk = 0; kk < BK; ++kk) {
            const float4 a0 = *reinterpret_cast<const float4*>(&As[kk][ty * 8]);
            const float4 a1 = *reinterpret_cast<const float4*>(&As[kk][ty * 8 + 4]);
            const float4 b0 = *reinterpret_cast<const float4*>(&Bs[kk][tx * 4]);
            const float av[8] = {a0.x, a0.y, a0.z, a0.w, a1.x, a1.y, a1.z, a1.w};
            const float bv[4] = {b0.x, b0.y, b0.z, b0.w};
#pragma unroll
            for (int i = 0; i < 8; ++i)
#pragma unroll
                for (int j = 0; j < 4; ++j)
                    acc[i][j] = fmaf(av[i], bv[j], acc[i][j]);
        }
        __syncthreads();
    }

#pragma unroll
    for (int i = 0; i < 8; ++i) {
        const int m = m0 + ty * 8 + i;
        const int n = n0 + tx * 4;
        const float4 o4 = make_float4(acc[i][0], acc[i][1], acc[i][2], acc[i][3]);
        size_t idx;
        if (remap_bhtd) {
            const int b = m >> 11;          // / T_
            const int t = m & (T_ - 1);
            const int h = n >> 6;           // / DH_  (BN==DH_, so one head/block-col pair)
            const int d = n & (DH_ - 1);
            idx = (((size_t)b * H_ + h) * T_ + t) * DH_ + d;
        } else {
            idx = (size_t)m * N + n;
        }
        *reinterpret_cast<float4*>(&C[idx]) = o4;
    }
}

// ---------------------------------------------------------------------------
// Flash attention, fp32.  Q,K,V: [B*H, T, DH].  Y: [B, T, D] (heads re-merged).
// Block: 256 threads; one 64-row Q tile of one (b,h); K/V tiles of 64.
// kpu is a union buffer: K^T during QK^T, then P^T during PV (saves LDS, keeps
// static shared under 64 KB: 16K + 16K + 17.4K = 50 KB).
// ---------------------------------------------------------------------------
__global__ __launch_bounds__(256)
void attn_fp32(const float* __restrict__ Q, const float* __restrict__ K,
               const float* __restrict__ V, float* __restrict__ Y)
{
    __shared__ float qsT[DH_][64];       // [d][q]
    __shared__ float vt [64][DH_];       // [k][d]
    __shared__ float kpu[64][68];        // phase1: [d][k]=K^T ; phase2: [k][q]=P^T

    const int tid = threadIdx.x;
    const int tx  = tid & 15;            // k-cols (QK^T) / d-cols (PV)
    const int ty  = tid >> 4;            // q-rows
    const int bh  = blockIdx.y;          // b*H + h
    const int t0  = blockIdx.x * 64;
    const size_t base = (size_t)bh * T_ * DH_;

    // Q tile -> qsT (transposed), once per block
#pragma unroll
    for (int it = 0; it < 4; ++it) {
        const int idx = it * 256 + tid;
        const int r   = idx >> 4;
        const int dd  = (idx & 15) << 2;
        const float4 q4 = *reinterpret_cast<const float4*>(
            &Q[base + (size_t)(t0 + r) * DH_ + dd]);
        qsT[dd + 0][r] = q4.x; qsT[dd + 1][r] = q4.y;
        qsT[dd + 2][r] = q4.z; qsT[dd + 3][r] = q4.w;
    }

    float o[4][4];
    float mrun[4], lrun[4];
#pragma unroll
    for (int i = 0; i < 4; ++i) {
        mrun[i] = -INFINITY; lrun[i] = 0.f;
#pragma unroll
        for (int j = 0; j < 4; ++j) o[i][j] = 0.f;
    }

    for (int kt = 0; kt < T_ / 64; ++kt) {
        __syncthreads();   // prev PV readers done; also covers qsT writes (kt=0)

        // K tile -> kpu (transposed), V tile -> vt (straight)
#pragma unroll
        for (int it = 0; it < 4; ++it) {
            const int idx = it * 256 + tid;
            const int r   = idx >> 4;
            const int dd  = (idx & 15) << 2;
            const size_t g = base + (size_t)(kt * 64 + r) * DH_ + dd;
            const float4 k4 = *reinterpret_cast<const float4*>(&K[g]);
            kpu[dd + 0][r] = k4.x; kpu[dd + 1][r] = k4.y;
            kpu[dd + 2][r] = k4.z; kpu[dd + 3][r] = k4.w;
            const float4 v4 = *reinterpret_cast<const float4*>(&V[g]);
            *reinterpret_cast<float4*>(&vt[r][dd]) = v4;
        }
        __syncthreads();

        // QK^T: S[q][k], 4x4 per thread
        float s[4][4];
#pragma unroll
        for (int i = 0; i < 4; ++i)
#pragma unroll
            for (int j = 0; j < 4; ++j) s[i][j] = 0.f;
#pragma unroll 8
        for (int d = 0; d < DH_; ++d) {
            const float4 qa = *reinterpret_cast<const float4*>(&qsT[d][ty * 4]);
            const float4 kb = *reinterpret_cast<const float4*>(&kpu[d][tx * 4]);
            const float av[4] = {qa.x, qa.y, qa.z, qa.w};
            const float bv[4] = {kb.x, kb.y, kb.z, kb.w};
#pragma unroll
            for (int i = 0; i < 4; ++i)
#pragma unroll
                for (int j = 0; j < 4; ++j)
                    s[i][j] = fmaf(av[i], bv[j], s[i][j]);
        }
        __syncthreads();   // all threads done reading kpu as K^T

        // online softmax; rows live in 16-lane groups (same ty)
#pragma unroll
        for (int i = 0; i < 4; ++i) {
            float rm = -INFINITY;
#pragma unroll
            for (int j = 0; j < 4; ++j) {
                s[i][j] *= 0.125f;               // 1/sqrt(DH)
                rm = fmaxf(rm, s[i][j]);
            }
#pragma unroll
            for (int off = 1; off < 16; off <<= 1)
                rm = fmaxf(rm, __shfl_xor(rm, off));
            const float mnew = fmaxf(mrun[i], rm);
            const float sc   = __expf(mrun[i] - mnew);   // exp(-inf)=0 on first tile
            mrun[i] = mnew;
            float rs = 0.f;
#pragma unroll
            for (int j = 0; j < 4; ++j) {
                s[i][j] = __expf(s[i][j] - mnew);
                rs += s[i][j];
            }
#pragma unroll
            for (int off = 1; off < 16; off <<= 1)
                rs += __shfl_xor(rs, off);
            lrun[i] = lrun[i] * sc + rs;
#pragma unroll
            for (int j = 0; j < 4; ++j) o[i][j] *= sc;
            // P^T into the union buffer
#pragma unroll
            for (int j = 0; j < 4; ++j)
                kpu[tx * 4 + j][ty * 4 + i] = s[i][j];
        }
        __syncthreads();

        // PV: O += P @ V
#pragma unroll 8
        for (int k = 0; k < 64; ++k) {
            const float4 pa = *reinterpret_cast<const float4*>(&kpu[k][ty * 4]);
            const float4 vb = *reinterpret_cast<const float4*>(&vt[k][tx * 4]);
            const float av[4] = {pa.x, pa.y, pa.z, pa.w};
            const float bv[4] = {vb.x, vb.y, vb.z, vb.w};
#pragma unroll
            for (int i = 0; i < 4; ++i)
#pragma unroll
                for (int j = 0; j < 4; ++j)
                    o[i][j] = fmaf(av[i], bv[j], o[i][j]);
        }
    }

    // epilogue: normalize and merge heads back to [B,T,D]
    const int b = bh >> 4;   // / H_
    const int h = bh & 15;
#pragma unroll
    for (int i = 0; i < 4; ++i) {
        const float inv = 1.f / lrun[i];
        const int t = t0 + ty * 4 + i;
        const float4 o4 = make_float4(o[i][0] * inv, o[i][1] * inv,
                                      o[i][2] * inv, o[i][3] * inv);
        *reinterpret_cast<float4*>(
            &Y[((size_t)b * T_ + t) * D_ + h * DH_ + tx * 4]) = o4;
    }
}

// ---------------------------------------------------------------------------
extern "C" void kernel_launch(void* const* d_in, const int* in_sizes, int n_in,
                              void* d_out, int out_size, void* d_ws, size_t ws_size,
                              hipStream_t stream)
{
    const float* x  = (const float*)d_in[0];
    const float* Wq = (const float*)d_in[1];
    const float* Wk = (const float*)d_in[2];
    const float* Wv = (const float*)d_in[3];
    const float* Wo = (const float*)d_in[4];
    float* out = (float*)d_out;

    // workspace: q,k,v ([B,H,T,DH]) + y ([B,T,D]) = 4 x 16 MB fp32
    const size_t n = (size_t)M_ * D_;
    float* q = (float*)d_ws;
    float* k = q + n;
    float* v = k + n;
    float* y = v + n;

    dim3 blk(256);
    dim3 gg(D_ / 64, M_ / 128);        // (16, 32) = 512 blocks
    gemm_abt<<<gg, blk, 0, stream>>>(x, Wq, q, M_, D_, D_, 1);
    gemm_abt<<<gg, blk, 0, stream>>>(x, Wk, k, M_, D_, D_, 1);
    gemm_abt<<<gg, blk, 0, stream>>>(x, Wv, v, M_, D_, D_, 1);

    dim3 ga(T_ / 64, B_ * H_);         // (32, 32) = 1024 blocks
    attn_fp32<<<ga, blk, 0, stream>>>(q, k, v, y);

    gemm_abt<<<gg, blk, 0, stream>>>(y, Wo, out, M_, D_, D_, 0);
}

// Round 2
// 288.009 us; speedup vs baseline: 3.5748x; 3.5748x over previous
//
#include <hip/hip_runtime.h>
#include <math.h>

typedef __attribute__((ext_vector_type(8))) short bf16x8;       // 8 bf16 (4 VGPR)
typedef __attribute__((ext_vector_type(8))) _Float16 half8;     // 8 fp16
typedef __attribute__((ext_vector_type(4))) float f32x4;

namespace {
constexpr int T_ = 2048, DH_ = 64;
constexpr int M_ = 4096;          // B*T
constexpr int KS = 2048;          // split row stride ([hi 0..1023 | lo 1024..2047])
}

__device__ __forceinline__ unsigned short bf16_rne(float f) {
    unsigned u = __float_as_uint(f);
    return (unsigned short)((u + 0x7fffu + ((u >> 16) & 1u)) >> 16);
}

// ---------------------------------------------------------------------------
// fp32 [rows][1024] -> split-bf16 [rows][2048] ([hi half | lo half])
// one thread = 4 elements; grid = rows blocks of 256
// ---------------------------------------------------------------------------
__global__ __launch_bounds__(256)
void split_bf16_k(const float* __restrict__ src, unsigned short* __restrict__ dst)
{
    const int i = blockIdx.x * 256 + threadIdx.x;
    const int r = i >> 8;
    const int c = (i & 255) << 2;
    const float4 f = *reinterpret_cast<const float4*>(src + (size_t)r * 1024 + c);
    const float vf[4] = {f.x, f.y, f.z, f.w};
    unsigned short hi[4], lo[4];
#pragma unroll
    for (int j = 0; j < 4; ++j) {
        hi[j] = bf16_rne(vf[j]);
        const float fh = __uint_as_float((unsigned)hi[j] << 16);
        lo[j] = bf16_rne(vf[j] - fh);
    }
    unsigned short* o = dst + (size_t)r * KS + c;
    *reinterpret_cast<ushort4*>(o)        = make_ushort4(hi[0], hi[1], hi[2], hi[3]);
    *reinterpret_cast<ushort4*>(o + 1024) = make_ushort4(lo[0], lo[1], lo[2], lo[3]);
}

// ---------------------------------------------------------------------------
// Split-bf16 GEMM: C = A @ W^T, exact-ish via 3 passes (hi*hi + hi*lo + lo*hi).
// A:[Ma][2048] bf16 split, Bw:[N][2048] bf16 split. Tile 128x64, BK=64,
// 256 thr = 4 waves (2m x 2n), wave-tile 64x32 (4x2 frags of 16x16x32).
// LDS rows 128 B, XOR-swizzled (slot ^ row&7) via pre-swizzled global source
// (global_load_lds writes linearly; read applies the same XOR).
// mode 0: scatter epilogue -> q/k fp16 [bh][t][dh], v fp16 [bh][dh][t]  (N=3072)
// mode 1: fp32 [m][1024] -> Cout                                        (N=1024)
// ---------------------------------------------------------------------------
__global__ __launch_bounds__(256)
void gemm_split(const unsigned short* __restrict__ A,
                const unsigned short* __restrict__ Bw,
                float* __restrict__ Cout,
                _Float16* __restrict__ qh, _Float16* __restrict__ kh,
                _Float16* __restrict__ vh, const int mode)
{
    __shared__ unsigned short As[128 * 64];   // 16 KB
    __shared__ unsigned short Bs[64 * 64];    //  8 KB
    const int tid = threadIdx.x;
    const int l   = tid & 63;
    const int w   = tid >> 6;
    const int wm  = w >> 1, wn = w & 1;
    const int m0  = blockIdx.y * 128;
    const int n0  = blockIdx.x * 64;

    f32x4 acc[4][2];
#pragma unroll
    for (int i = 0; i < 4; ++i)
#pragma unroll
        for (int j = 0; j < 2; ++j) acc[i][j] = (f32x4){0.f, 0.f, 0.f, 0.f};

    // staging decomposition: one global_load_lds = 8 rows x 128 B (64 lanes x 16 B)
    const int srow  = l >> 3;                    // row within instr (0..7)
    const int scol  = ((l & 7) ^ (srow & 7)) << 3;  // pre-swizzled elem col
    // frag read decomposition
    const int frow = l & 15;
    const int fkb  = (l >> 4) << 4;              // byte k-offset within 32-elem step

    for (int vt = 0; vt < 48; ++vt) {
        const int pass = vt >> 4;
        const int kt   = (vt & 15) << 6;
        const int ka   = kt + ((pass == 2) ? 1024 : 0);
        const int kb   = kt + ((pass == 1) ? 1024 : 0);
#pragma unroll
        for (int s = 0; s < 4; ++s) {            // A tile: 16 instrs, 4/wave
            const int j = (w << 2) + s;
            const unsigned short* gp = A + (size_t)(m0 + (j << 3) + srow) * KS + ka + scol;
            __builtin_amdgcn_global_load_lds(
                (const __attribute__((address_space(1))) void*)gp,
                (__attribute__((address_space(3))) void*)(As + (j << 9)), 16, 0, 0);
        }
#pragma unroll
        for (int s = 0; s < 2; ++s) {            // B tile: 8 instrs, 2/wave
            const int j = (w << 1) + s;
            const unsigned short* gp = Bw + (size_t)(n0 + (j << 3) + srow) * KS + kb + scol;
            __builtin_amdgcn_global_load_lds(
                (const __attribute__((address_space(1))) void*)gp,
                (__attribute__((address_space(3))) void*)(Bs + (j << 9)), 16, 0, 0);
        }
        __syncthreads();   // compiler drains vmcnt before barrier
#pragma unroll
        for (int ks = 0; ks < 2; ++ks) {
            bf16x8 af[4], bfr[2];
#pragma unroll
            for (int fi = 0; fi < 4; ++fi) {
                const int row = wm * 64 + fi * 16 + frow;
                const int cb  = (ks * 64 + fkb) ^ ((row & 7) << 4);
                af[fi] = *reinterpret_cast<const bf16x8*>(
                    reinterpret_cast<const char*>(As) + row * 128 + cb);
            }
#pragma unroll
            for (int fj = 0; fj < 2; ++fj) {
                const int row = wn * 32 + fj * 16 + frow;
                const int cb  = (ks * 64 + fkb) ^ ((row & 7) << 4);
                bfr[fj] = *reinterpret_cast<const bf16x8*>(
                    reinterpret_cast<const char*>(Bs) + row * 128 + cb);
            }
#pragma unroll
            for (int fi = 0; fi < 4; ++fi)
#pragma unroll
                for (int fj = 0; fj < 2; ++fj)
                    acc[fi][fj] = __builtin_amdgcn_mfma_f32_16x16x32_bf16(
                        af[fi], bfr[fj], acc[fi][fj], 0, 0, 0);
        }
        __syncthreads();
    }

    const int r0 = (l >> 4) << 2;
#pragma unroll
    for (int fi = 0; fi < 4; ++fi)
#pragma unroll
        for (int fj = 0; fj < 2; ++fj)
#pragma unroll
            for (int r = 0; r < 4; ++r) {
                const int m = m0 + wm * 64 + fi * 16 + r0 + r;
                const int n = n0 + wn * 32 + fj * 16 + (l & 15);
                const float vv = acc[fi][fj][r];
                if (mode == 0) {
                    const int bb = m >> 11, t = m & 2047;
                    const int which = n >> 10, nl = n & 1023;
                    const int hh = nl >> 6, dh = nl & 63;
                    const int bh = (bb << 4) + hh;
                    if (which == 0)
                        qh[(((size_t)bh << 11) + t) * 64 + dh] = (_Float16)vv;
                    else if (which == 1)
                        kh[(((size_t)bh << 11) + t) * 64 + dh] = (_Float16)vv;
                    else
                        vh[(((size_t)bh << 6) + dh) * 2048 + t] = (_Float16)vv;
                } else {
                    Cout[(size_t)m * 1024 + n] = vv;
                }
            }
}

// ---------------------------------------------------------------------------
// Flash attention, fp16 MFMA.  Qh,Kh:[bh][t][dh] fp16, Vh:[bh][dh][t] fp16
// (pre-transposed).  Output: Yw split-bf16 [4096][2048] for the Wo GEMM.
// 256 thr = 4 waves; block = 64 q-rows (16/wave), K/V tiles of 64.
// All LDS tiles [64][64] fp16 (128 B rows) XOR-swizzled: byte ^= (row&7)<<4.
// ---------------------------------------------------------------------------
#define SWZ(row, bytecol) (((row) << 7) + ((bytecol) ^ (((row) & 7) << 4)))

__global__ __launch_bounds__(256)
void attn_mfma(const _Float16* __restrict__ Qh, const _Float16* __restrict__ Kh,
               const _Float16* __restrict__ Vh, unsigned short* __restrict__ Yw)
{
    __shared__ _Float16 Qs[64 * 64];
    __shared__ _Float16 Ks[64 * 64];
    __shared__ _Float16 Vs[64 * 64];   // [d][key]
    __shared__ _Float16 Ps[64 * 64];   // [q][key]
    const int tid = threadIdx.x;
    const int l   = tid & 63;
    const int w   = tid >> 6;
    const int g4  = l >> 4;            // 4-row group
    const int c16 = l & 15;
    const int bh  = blockIdx.y;
    const int t0  = blockIdx.x * 64;
    const size_t qkbase = (size_t)bh * T_ * DH_;
    const size_t vbase  = (size_t)bh * DH_ * T_;

    {   // stage Q tile (rows 128 B = 8 segs; 2 segs/thread)
        const int r = tid >> 2;
#pragma unroll
        for (int s2 = 0; s2 < 2; ++s2) {
            const int s = (tid & 3) + (s2 << 2);
            const uint4 d = *reinterpret_cast<const uint4*>(
                Qh + qkbase + (size_t)(t0 + r) * 64 + (s << 3));
            *reinterpret_cast<uint4*>(reinterpret_cast<char*>(Qs) + SWZ(r, s << 4)) = d;
        }
    }
    __syncthreads();

    half8 qf[2];
#pragma unroll
    for (int ks = 0; ks < 2; ++ks) {
        const int row = w * 16 + c16;
        qf[ks] = *reinterpret_cast<const half8*>(
            reinterpret_cast<const char*>(Qs) + SWZ(row, ks * 64 + (g4 << 4)));
    }

    f32x4 o[4];
    float mrun[4], lrun[4];
#pragma unroll
    for (int i = 0; i < 4; ++i) {
        o[i] = (f32x4){0.f, 0.f, 0.f, 0.f};
        mrun[i] = -INFINITY; lrun[i] = 0.f;
    }

    for (int ktile = 0; ktile < T_ / 64; ++ktile) {
        __syncthreads();   // all waves done reading Ks/Vs of previous tile
        {
            const int r = tid >> 2;
#pragma unroll
            for (int s2 = 0; s2 < 2; ++s2) {
                const int s = (tid & 3) + (s2 << 2);
                const uint4 kd = *reinterpret_cast<const uint4*>(
                    Kh + qkbase + (size_t)(ktile * 64 + r) * 64 + (s << 3));
                *reinterpret_cast<uint4*>(reinterpret_cast<char*>(Ks) + SWZ(r, s << 4)) = kd;
                const uint4 vd = *reinterpret_cast<const uint4*>(
                    Vh + vbase + (size_t)r * T_ + ktile * 64 + (s << 3));
                *reinterpret_cast<uint4*>(reinterpret_cast<char*>(Vs) + SWZ(r, s << 4)) = vd;
            }
        }
        __syncthreads();

        // S = Q K^T  (wave w owns q-rows w*16..+15; 4 key-frags)
        f32x4 s[4];
#pragma unroll
        for (int fj = 0; fj < 4; ++fj) s[fj] = (f32x4){0.f, 0.f, 0.f, 0.f};
#pragma unroll
        for (int ks = 0; ks < 2; ++ks)
#pragma unroll
            for (int fj = 0; fj < 4; ++fj) {
                const int row = fj * 16 + c16;   // key
                const half8 kf = *reinterpret_cast<const half8*>(
                    reinterpret_cast<const char*>(Ks) + SWZ(row, ks * 64 + (g4 << 4)));
                s[fj] = __builtin_amdgcn_mfma_f32_16x16x32_f16(qf[ks], kf, s[fj], 0, 0, 0);
            }

        // online softmax (rows q = w*16 + 4*g4 + r4; 16-lane groups share rows)
#pragma unroll
        for (int fj = 0; fj < 4; ++fj) s[fj] = s[fj] * 0.125f;
#pragma unroll
        for (int r4 = 0; r4 < 4; ++r4) {
            float mr = fmaxf(fmaxf(s[0][r4], s[1][r4]), fmaxf(s[2][r4], s[3][r4]));
#pragma unroll
            for (int off = 1; off < 16; off <<= 1) mr = fmaxf(mr, __shfl_xor(mr, off));
            const float mnew = fmaxf(mrun[r4], mr);
            const float sc   = __expf(mrun[r4] - mnew);
            mrun[r4] = mnew;
            float pv[4], rs = 0.f;
#pragma unroll
            for (int fj = 0; fj < 4; ++fj) {
                pv[fj] = __expf(s[fj][r4] - mnew);
                rs += pv[fj];
            }
#pragma unroll
            for (int off = 1; off < 16; off <<= 1) rs += __shfl_xor(rs, off);
            lrun[r4] = lrun[r4] * sc + rs;
#pragma unroll
            for (int fj = 0; fj < 4; ++fj) o[fj][r4] *= sc;
            const int q = w * 16 + (g4 << 2) + r4;
#pragma unroll
            for (int fj = 0; fj < 4; ++fj)
                *reinterpret_cast<_Float16*>(reinterpret_cast<char*>(Ps) +
                    SWZ(q, fj * 32 + (c16 << 1))) = (_Float16)pv[fj];
        }

        // O += P V  (own-wave P rows -> no barrier needed before reads)
#pragma unroll
        for (int ks = 0; ks < 2; ++ks) {
            const int prow = w * 16 + c16;
            const half8 pf = *reinterpret_cast<const half8*>(
                reinterpret_cast<const char*>(Ps) + SWZ(prow, ks * 64 + (g4 << 4)));
#pragma unroll
            for (int fj = 0; fj < 4; ++fj) {
                const int vrow = fj * 16 + c16;  // d
                const half8 vf = *reinterpret_cast<const half8*>(
                    reinterpret_cast<const char*>(Vs) + SWZ(vrow, ks * 64 + (g4 << 4)));
                o[fj] = __builtin_amdgcn_mfma_f32_16x16x32_f16(pf, vf, o[fj], 0, 0, 0);
            }
        }
    }

    // epilogue: normalize, split to bf16 hi/lo, store to Yw [4096][2048]
    const int bb = bh >> 4, hh = bh & 15;
#pragma unroll
    for (int r4 = 0; r4 < 4; ++r4) {
        const int t = t0 + w * 16 + (g4 << 2) + r4;
        const float inv = 1.f / lrun[r4];
        const size_t mrow = ((size_t)bb * T_ + t) * KS;
#pragma unroll
        for (int fj = 0; fj < 4; ++fj) {
            const int col = hh * 64 + fj * 16 + c16;
            const float vv = o[fj][r4] * inv;
            const unsigned short h16 = bf16_rne(vv);
            const float fh = __uint_as_float((unsigned)h16 << 16);
            Yw[mrow + col]        = h16;
            Yw[mrow + 1024 + col] = bf16_rne(vv - fh);
        }
    }
}

// ---------------------------------------------------------------------------
extern "C" void kernel_launch(void* const* d_in, const int* in_sizes, int n_in,
                              void* d_out, int out_size, void* d_ws, size_t ws_size,
                              hipStream_t stream)
{
    const float* x  = (const float*)d_in[0];
    const float* Wq = (const float*)d_in[1];
    const float* Wk = (const float*)d_in[2];
    const float* Wv = (const float*)d_in[3];
    const float* Wo = (const float*)d_in[4];

    unsigned char* ws = (unsigned char*)d_ws;
    unsigned short* xw = (unsigned short*)ws;                       // [4096][2048] bf16
    unsigned short* Ww = (unsigned short*)(ws + (size_t)16777216);  // [4096][2048] (Wq|Wk|Wv|Wo rows)
    _Float16* qh = (_Float16*)(ws + (size_t)33554432);              // [32][2048][64]
    _Float16* kh = (_Float16*)(ws + (size_t)41943040);
    _Float16* vh = (_Float16*)(ws + (size_t)50331648);              // [32][64][2048]
    unsigned short* yw = xw;   // x-split dead after QKV GEMM; attn output aliases it

    split_bf16_k<<<4096, 256, 0, stream>>>(x, xw);
    split_bf16_k<<<1024, 256, 0, stream>>>(Wq, Ww);
    split_bf16_k<<<1024, 256, 0, stream>>>(Wk, Ww + (size_t)1024 * KS);
    split_bf16_k<<<1024, 256, 0, stream>>>(Wv, Ww + (size_t)2048 * KS);
    split_bf16_k<<<1024, 256, 0, stream>>>(Wo, Ww + (size_t)3072 * KS);

    dim3 blk(256);
    dim3 g1(48, 32);   // N=3072, M=4096: fused QKV projection
    gemm_split<<<g1, blk, 0, stream>>>(xw, Ww, nullptr, qh, kh, vh, 0);

    dim3 ga(T_ / 64, 32);
    attn_mfma<<<ga, blk, 0, stream>>>(qh, kh, vh, yw);

    dim3 g2(16, 32);   // N=1024: output projection
    gemm_split<<<g2, blk, 0, stream>>>(yw, Ww + (size_t)3072 * KS, (float*)d_out,
                                       nullptr, nullptr, nullptr, 1);
}